// Round 7
// baseline (108.882 us; speedup 1.0000x reference)
//
#include <hip/hip_runtime.h>
#include <hip/hip_bf16.h>
#include <hip/hip_fp16.h>

#define NPTS 262144
#define EMB  256
#define RES  512
#define NROWS (4 * RES)        // 2048 table rows
#define NCELL (128 * 128)      // 2D spatial cells (4 table-rows per cell side)

typedef _Float16 half_t;
typedef __attribute__((ext_vector_type(8))) _Float16 half8;
typedef __attribute__((ext_vector_type(2))) _Float16 half2v;

// ---------------------------------------------------------------------------
// ws layout:
//   [0, 1MiB)                 T2 table, fp16 [2048][256]
//   [1MiB, +64KiB)            hist   (16384 int)   -- memset 0 each launch
//   [1MiB+64K, +64KiB)        cursor (16384 int)   -- rewritten by scan
//   [1MiB+128K, +2MiB)        pcoords (float2[N], cell-ordered, clamped)
//   [3MiB+128K, +1MiB)        pidx    (int[N], original point index)
// ---------------------------------------------------------------------------

__device__ __forceinline__ int cell_of(float x, float y) {
    const float cx = fminf(fmaxf(x, -1.f), 0.999f);
    const float cy = fminf(fmaxf(y, -1.f), 0.999f);
    const int rx = (int)fmaf(cx, 255.5f, 255.5f);   // 0..510
    const int ry = (int)fmaf(cy, 255.5f, 255.5f);
    return ((ry >> 2) << 7) | (rx >> 2);            // 128x128 cells
}

// ---------------------------------------------------------------------------
// Kernel 1: T2[a,i,o] = (30/4)/(2pi) * sum_e tables[a,i,e] * W1[o,e], fp16.
// ---------------------------------------------------------------------------
__global__ __launch_bounds__(256) void t2_precompute_kernel(
    const float* __restrict__ tables,   // [4][512][256]
    const float* __restrict__ W1,       // [256][256]
    half_t* __restrict__ T2)            // [2048][256]
{
    __shared__ __align__(16) float arow[8][EMB];
    const int row0 = blockIdx.x * 8;
    const int o = threadIdx.x;

    #pragma unroll
    for (int r = 0; r < 8; ++r)
        arow[r][o] = tables[(row0 + r) * EMB + o];
    __syncthreads();

    float acc[8] = {0.f, 0.f, 0.f, 0.f, 0.f, 0.f, 0.f, 0.f};
    const float4* __restrict__ w1v = reinterpret_cast<const float4*>(W1 + o * EMB);
    for (int ec = 0; ec < EMB / 4; ++ec) {
        const float4 w4 = w1v[ec];
        #pragma unroll
        for (int r = 0; r < 8; ++r) {
            const float4 a4 = *reinterpret_cast<const float4*>(&arow[r][ec * 4]);
            acc[r] = fmaf(w4.x, a4.x, acc[r]);
            acc[r] = fmaf(w4.y, a4.y, acc[r]);
            acc[r] = fmaf(w4.z, a4.z, acc[r]);
            acc[r] = fmaf(w4.w, a4.w, acc[r]);
        }
    }
    const float s = 7.5f * 0.15915494309189535f;   // (30/4)/(2pi)
    #pragma unroll
    for (int r = 0; r < 8; ++r)
        T2[(row0 + r) * EMB + o] = (half_t)(s * acc[r]);
}

// ---------------------------------------------------------------------------
// Binning pass 1: per-cell histogram.
// ---------------------------------------------------------------------------
__global__ __launch_bounds__(256) void hist_kernel(
    const float* __restrict__ coords, int* __restrict__ hist)
{
    const int p = blockIdx.x * 256 + threadIdx.x;
    const float x = coords[2 * p], y = coords[2 * p + 1];
    atomicAdd(&hist[cell_of(x, y)], 1);
}

// ---------------------------------------------------------------------------
// Binning pass 2: exclusive scan of 16384 cell counts (single 1024-thr block).
// ---------------------------------------------------------------------------
__global__ __launch_bounds__(1024) void scan_kernel(
    const int* __restrict__ hist, int* __restrict__ cursor)
{
    __shared__ int ls[1024];
    const int t = threadIdx.x;
    int loc[16]; int s = 0;
    #pragma unroll
    for (int i = 0; i < 16; ++i) { loc[i] = hist[t * 16 + i]; s += loc[i]; }
    ls[t] = s;
    __syncthreads();
    for (int d = 1; d < 1024; d <<= 1) {
        int v = 0;
        if (t >= d) v = ls[t - d];
        __syncthreads();
        ls[t] += v;
        __syncthreads();
    }
    int run = ls[t] - s;   // exclusive offset for this thread's 16 cells
    #pragma unroll
    for (int i = 0; i < 16; ++i) { cursor[t * 16 + i] = run; run += loc[i]; }
}

// ---------------------------------------------------------------------------
// Binning pass 3: scatter points into cell order (coords pre-clamped).
// ---------------------------------------------------------------------------
__global__ __launch_bounds__(256) void scatter_kernel(
    const float* __restrict__ coords, int* __restrict__ cursor,
    float2* __restrict__ pcoords, int* __restrict__ pidx)
{
    const int p = blockIdx.x * 256 + threadIdx.x;
    const float x = coords[2 * p], y = coords[2 * p + 1];
    const int idx = atomicAdd(&cursor[cell_of(x, y)], 1);
    pcoords[idx] = make_float2(fminf(fmaxf(x, -1.f), 1.f),
                               fminf(fmaxf(y, -1.f), 1.f));
    pidx[idx] = p;
}

// ---------------------------------------------------------------------------
// DPP butterfly add over 16 lanes (xor1, xor2, half-mirror, mirror) — VALU.
// ctrl must be a compile-time constant -> template parameter.
// ---------------------------------------------------------------------------
template <int CTRL>
__device__ __forceinline__ float dpp_add(float v) {
    const int vi = __builtin_bit_cast(int, v);
    const int sh = __builtin_amdgcn_update_dpp(0, vi, CTRL, 0xF, 0xF, true);
    return v + __builtin_bit_cast(float, sh);
}
__device__ __forceinline__ float reduce16(float v) {
    v = dpp_add<0xB1>(v);    // quad_perm [1,0,3,2] : xor 1
    v = dpp_add<0x4E>(v);    // quad_perm [2,3,0,1] : xor 2
    v = dpp_add<0x141>(v);   // row_half_mirror     : covers bit 2
    v = dpp_add<0x140>(v);   // row_mirror          : covers bit 3
    return v;
}

// ---------------------------------------------------------------------------
// Kernel 5: eval over cell-ordered points. 16 lanes/point, 4 points/wave,
// wave owns 8 CONTIGUOUS quads (32 consecutive permuted points -> shared
// cells -> T2 rows L1-resident). Block-index swizzle clusters co-resident
// blocks onto adjacent chunks.
// ---------------------------------------------------------------------------
__global__ __launch_bounds__(256, 4) void eval_kernel(
    const float2* __restrict__ pcoords,    // [N] cell-ordered, clamped
    const int* __restrict__ pidx,          // [N] original index
    const half_t* __restrict__ T2,         // [2048][256]
    const float* __restrict__ b1,
    const float* __restrict__ W2,
    const float* __restrict__ b2,
    float* __restrict__ out)
{
    const int lane = threadIdx.x & 63;
    const int g    = lane >> 4;
    const int l16  = lane & 15;
    const int dA   = l16 * 8;
    const int dB   = 128 + l16 * 8;

    // swizzle: co-resident blocks (b, b+256, ...) -> adjacent chunks
    const int bb   = ((blockIdx.x & 255) << 3) | (blockIdx.x >> 8);
    const int wave = bb * 4 + (threadIdx.x >> 6);

    const float sb = 30.f * 0.15915494309189535f;
    half8 biasA, biasB;
    #pragma unroll
    for (int i = 0; i < 8; ++i) {
        biasA[i] = (half_t)(sb * b1[dA + i]);
        biasB[i] = (half_t)(sb * b1[dB + i]);
    }
    half2v w2p[3][8];
    #pragma unroll
    for (int j = 0; j < 3; ++j)
        #pragma unroll
        for (int k = 0; k < 4; ++k) {
            w2p[j][k][0]     = (half_t)W2[j * EMB + dA + 2 * k];
            w2p[j][k][1]     = (half_t)W2[j * EMB + dA + 2 * k + 1];
            w2p[j][4 + k][0] = (half_t)W2[j * EMB + dB + 2 * k];
            w2p[j][4 + k][1] = (half_t)W2[j * EMB + dB + 2 * k + 1];
        }
    const float ob0 = b2[0], ob1 = b2[1], ob2 = b2[2];
    const char* __restrict__ T2b = reinterpret_cast<const char*>(T2) + (l16 << 4);

    const int q0i = wave * 8;
    for (int q = q0i; q < q0i + 8; ++q) {
        const int pp = 4 * q + g;
        const float2 cf = pcoords[pp];
        const int op = pidx[pp];
        const float x = cf.x, y = cf.y;

        int rb[4];
        half_t hw[4], homw[4];
        #pragma unroll
        for (int a = 0; a < 4; ++a) {
            float c = (a == 0) ? x : (a == 1) ? y
                    : (a == 2) ? 0.5f * (x + y) : 0.5f * (x - y);
            c = fminf(fmaxf(c, -1.f), 0.999f);
            const float t  = fmaf(c, 255.5f, 255.5f);
            const float fi = floorf(t);
            const float w  = t - fi;
            hw[a]   = (half_t)w;
            homw[a] = (half_t)(1.f - w);
            rb[a]   = (((a << 9) + (int)fi) << 9);
        }

        half8 A0[4], B0[4], A1[4], B1[4];
        #pragma unroll
        for (int a = 0; a < 4; ++a) {
            const char* base = T2b + rb[a];
            A0[a] = *reinterpret_cast<const half8*>(base);
            B0[a] = *reinterpret_cast<const half8*>(base + 256);
            A1[a] = *reinterpret_cast<const half8*>(base + 512);
            B1[a] = *reinterpret_cast<const half8*>(base + 768);
        }

        half8 accA = biasA, accB = biasB;
        #pragma unroll
        for (int a = 0; a < 4; ++a) {
            accA = A0[a] * homw[a] + accA;
            accA = A1[a] * hw[a]   + accA;
            accB = B0[a] * homw[a] + accB;
            accB = B1[a] * hw[a]   + accB;
        }

        float q0 = 0.f, q1 = 0.f, q2 = 0.f;
        #pragma unroll
        for (int k = 0; k < 4; ++k) {
            const float s0 = __builtin_amdgcn_sinf((float)accA[2 * k]);
            const float s1 = __builtin_amdgcn_sinf((float)accA[2 * k + 1]);
#if __has_builtin(__builtin_amdgcn_fdot2)
            const half2v hp = __builtin_bit_cast(half2v, __builtin_amdgcn_cvt_pkrtz(s0, s1));
            q0 = __builtin_amdgcn_fdot2(hp, w2p[0][k], q0, false);
            q1 = __builtin_amdgcn_fdot2(hp, w2p[1][k], q1, false);
            q2 = __builtin_amdgcn_fdot2(hp, w2p[2][k], q2, false);
#else
            q0 = fmaf(s0, (float)w2p[0][k][0], fmaf(s1, (float)w2p[0][k][1], q0));
            q1 = fmaf(s0, (float)w2p[1][k][0], fmaf(s1, (float)w2p[1][k][1], q1));
            q2 = fmaf(s0, (float)w2p[2][k][0], fmaf(s1, (float)w2p[2][k][1], q2));
#endif
        }
        #pragma unroll
        for (int k = 0; k < 4; ++k) {
            const float s0 = __builtin_amdgcn_sinf((float)accB[2 * k]);
            const float s1 = __builtin_amdgcn_sinf((float)accB[2 * k + 1]);
#if __has_builtin(__builtin_amdgcn_fdot2)
            const half2v hp = __builtin_bit_cast(half2v, __builtin_amdgcn_cvt_pkrtz(s0, s1));
            q0 = __builtin_amdgcn_fdot2(hp, w2p[0][4 + k], q0, false);
            q1 = __builtin_amdgcn_fdot2(hp, w2p[1][4 + k], q1, false);
            q2 = __builtin_amdgcn_fdot2(hp, w2p[2][4 + k], q2, false);
#else
            q0 = fmaf(s0, (float)w2p[0][4 + k][0], fmaf(s1, (float)w2p[0][4 + k][1], q0));
            q1 = fmaf(s0, (float)w2p[1][4 + k][0], fmaf(s1, (float)w2p[1][4 + k][1], q1));
            q2 = fmaf(s0, (float)w2p[2][4 + k][0], fmaf(s1, (float)w2p[2][4 + k][1], q2));
#endif
        }

        q0 = reduce16(q0);
        q1 = reduce16(q1);
        q2 = reduce16(q2);

        if (l16 == 0) {
            out[3 * op + 0] = q0 + ob0;
            out[3 * op + 1] = q1 + ob1;
            out[3 * op + 2] = q2 + ob2;
        }
    }
}

extern "C" void kernel_launch(void* const* d_in, const int* in_sizes, int n_in,
                              void* d_out, int out_size, void* d_ws, size_t ws_size,
                              hipStream_t stream) {
    const float* coords = (const float*)d_in[0];
    const float* tables = (const float*)d_in[1];
    const float* W1     = (const float*)d_in[2];
    const float* b1     = (const float*)d_in[3];
    const float* W2     = (const float*)d_in[4];
    const float* b2     = (const float*)d_in[5];
    float* out = (float*)d_out;

    char* ws = (char*)d_ws;
    half_t* T2      = (half_t*)(ws);                          // 1 MiB
    int*    hist    = (int*)   (ws + (1 << 20));              // 64 KiB
    int*    cursor  = (int*)   (ws + (1 << 20) + (1 << 16));  // 64 KiB
    float2* pcoords = (float2*)(ws + (1 << 20) + (2 << 16));  // 2 MiB
    int*    pidx    = (int*)   (ws + (3 << 20) + (2 << 16));  // 1 MiB

    hipLaunchKernelGGL(t2_precompute_kernel, dim3(NROWS / 8), dim3(256), 0, stream,
                       tables, W1, T2);
    (void)hipMemsetAsync(hist, 0, NCELL * sizeof(int), stream);
    hipLaunchKernelGGL(hist_kernel, dim3(NPTS / 256), dim3(256), 0, stream,
                       coords, hist);
    hipLaunchKernelGGL(scan_kernel, dim3(1), dim3(1024), 0, stream,
                       hist, cursor);
    hipLaunchKernelGGL(scatter_kernel, dim3(NPTS / 256), dim3(256), 0, stream,
                       coords, cursor, pcoords, pidx);
    hipLaunchKernelGGL(eval_kernel, dim3(2048), dim3(256), 0, stream,
                       pcoords, pidx, T2, b1, W2, b2, out);
}

// Round 8
// 55.325 us; speedup vs baseline: 1.9680x; 1.9680x over previous
//
#include <hip/hip_runtime.h>
#include <hip/hip_fp16.h>

#define NPTS 262144
#define EMB  256
#define NROWS 2048

typedef _Float16 half_t;
typedef __attribute__((ext_vector_type(8))) _Float16 half8;
typedef __attribute__((ext_vector_type(2))) _Float16 half2v;

// ---------------------------------------------------------------------------
// Kernel 1: T2[a,i,o] = (30/4)/(2pi) * sum_e tables[a,i,e] * W1[o,e], fp16.
// ---------------------------------------------------------------------------
__global__ __launch_bounds__(256) void t2_precompute_kernel(
    const float* __restrict__ tables,   // [4][512][256]
    const float* __restrict__ W1,       // [256][256]
    half_t* __restrict__ T2)            // [2048][256]
{
    __shared__ __align__(16) float arow[8][EMB];
    const int row0 = blockIdx.x * 8;
    const int o = threadIdx.x;

    #pragma unroll
    for (int r = 0; r < 8; ++r)
        arow[r][o] = tables[(row0 + r) * EMB + o];
    __syncthreads();

    float acc[8] = {0.f, 0.f, 0.f, 0.f, 0.f, 0.f, 0.f, 0.f};
    const float4* __restrict__ w1v = reinterpret_cast<const float4*>(W1 + o * EMB);
    for (int ec = 0; ec < EMB / 4; ++ec) {
        const float4 w4 = w1v[ec];
        #pragma unroll
        for (int r = 0; r < 8; ++r) {
            const float4 a4 = *reinterpret_cast<const float4*>(&arow[r][ec * 4]);
            acc[r] = fmaf(w4.x, a4.x, acc[r]);
            acc[r] = fmaf(w4.y, a4.y, acc[r]);
            acc[r] = fmaf(w4.z, a4.z, acc[r]);
            acc[r] = fmaf(w4.w, a4.w, acc[r]);
        }
    }
    const float s = 7.5f * 0.15915494309189535f;   // (30/4)/(2pi)
    #pragma unroll
    for (int r = 0; r < 8; ++r)
        T2[(row0 + r) * EMB + o] = (half_t)(s * acc[r]);
}

// ---------------------------------------------------------------------------
// DPP butterfly add over 16 lanes — VALU pipe, no LDS traffic.
// ---------------------------------------------------------------------------
template <int CTRL>
__device__ __forceinline__ float dpp_add(float v) {
    const int vi = __builtin_bit_cast(int, v);
    const int sh = __builtin_amdgcn_update_dpp(0, vi, CTRL, 0xF, 0xF, true);
    return v + __builtin_bit_cast(float, sh);
}
__device__ __forceinline__ float reduce16(float v) {
    v = dpp_add<0xB1>(v);    // quad_perm xor1
    v = dpp_add<0x4E>(v);    // quad_perm xor2
    v = dpp_add<0x141>(v);   // row_half_mirror
    v = dpp_add<0x140>(v);   // row_mirror
    return v;
}

// ---------------------------------------------------------------------------
// Kernel 2: 16 lanes/point, 4 points/wave, 8 iterations/wave, fully unrolled
// with a 2-deep software pipeline: iteration k+1's addresses computed and its
// 16 row loads issued while iteration k's lerp/sin/dot runs.
// ---------------------------------------------------------------------------
__global__ __launch_bounds__(256, 4) void eval_kernel(
    const float* __restrict__ coords,      // [N][2]
    const half_t* __restrict__ T2,         // [2048][256]
    const float* __restrict__ b1,
    const float* __restrict__ W2,
    const float* __restrict__ b2,
    float* __restrict__ out)
{
    const int lane = threadIdx.x & 63;
    const int g    = lane >> 4;            // point slot within wave
    const int l16  = lane & 15;
    const int dA   = l16 * 8;              // dims dA..dA+7   (row half A)
    const int dB   = 128 + l16 * 8;        // dims dB..dB+7   (row half B)

    const int wave   = blockIdx.x * 4 + (threadIdx.x >> 6);
    const int stride = gridDim.x * 4;      // 8192

    // ---- hoisted constants ----
    const float sb = 30.f * 0.15915494309189535f;
    half8 biasA, biasB;
    #pragma unroll
    for (int i = 0; i < 8; ++i) {
        biasA[i] = (half_t)(sb * b1[dA + i]);
        biasB[i] = (half_t)(sb * b1[dB + i]);
    }
    half2v w2A[3][4], w2B[3][4];
    #pragma unroll
    for (int j = 0; j < 3; ++j)
        #pragma unroll
        for (int k = 0; k < 4; ++k) {
            w2A[j][k][0] = (half_t)W2[j * EMB + dA + 2 * k];
            w2A[j][k][1] = (half_t)W2[j * EMB + dA + 2 * k + 1];
            w2B[j][k][0] = (half_t)W2[j * EMB + dB + 2 * k];
            w2B[j][k][1] = (half_t)W2[j * EMB + dB + 2 * k + 1];
        }
    const float ob0 = b2[0], ob1 = b2[1], ob2 = b2[2];

    int Ca[4];
    #pragma unroll
    for (int a = 0; a < 4; ++a) Ca[a] = (a << 18) + (l16 << 4);

    const char* __restrict__ T2b = reinterpret_cast<const char*>(T2);
    const float TMAX = 0.9995f * 511.0f;   // t-clamp for c<=0.999

    // ---- per-iteration helpers ----
    auto calc = [&](int pq, int rb[4], half2v pw[4], int& pOut) {
        const int p = 4 * pq + g;
        pOut = p;
        const float2 cf = *reinterpret_cast<const float2*>(coords + 2 * p);
        const float txr = __builtin_amdgcn_fmed3f(fmaf(cf.x, 255.5f, 255.5f), 0.f, 511.f);
        const float tyr = __builtin_amdgcn_fmed3f(fmaf(cf.y, 255.5f, 255.5f), 0.f, 511.f);
        float t[4];
        t[0] = fminf(txr, TMAX);
        t[1] = fminf(tyr, TMAX);
        t[2] = fminf((txr + tyr) * 0.5f, TMAX);
        t[3] = fminf(fmaf(txr - tyr, 0.5f, 255.5f), TMAX);
        #pragma unroll
        for (int a = 0; a < 4; ++a) {
            const int i0 = (int)t[a];
            const float w = t[a] - (float)i0;
            rb[a] = (i0 << 9) + Ca[a];
            pw[a] = __builtin_bit_cast(half2v,
                        __builtin_amdgcn_cvt_pkrtz(1.f - w, w));
        }
    };
    auto loadA = [&](const int rb[4], half8 A0[4], half8 A1[4]) {
        #pragma unroll
        for (int a = 0; a < 4; ++a) {
            A0[a] = *reinterpret_cast<const half8*>(T2b + rb[a]);
            A1[a] = *reinterpret_cast<const half8*>(T2b + rb[a] + 512);
        }
    };
    auto loadB = [&](const int rb[4], half8 B0[4], half8 B1[4]) {
        #pragma unroll
        for (int a = 0; a < 4; ++a) {
            B0[a] = *reinterpret_cast<const half8*>(T2b + rb[a] + 256);
            B1[a] = *reinterpret_cast<const half8*>(T2b + rb[a] + 768);
        }
    };
    auto dots = [&](const half8& acc, const half2v (&w2)[3][4],
                    float& q0, float& q1, float& q2) {
        #pragma unroll
        for (int k = 0; k < 4; ++k) {
            const float s0 = __builtin_amdgcn_sinf((float)acc[2 * k]);
            const float s1 = __builtin_amdgcn_sinf((float)acc[2 * k + 1]);
            const half2v hp = __builtin_bit_cast(half2v,
                                  __builtin_amdgcn_cvt_pkrtz(s0, s1));
            q0 = __builtin_amdgcn_fdot2(hp, w2[0][k], q0, false);
            q1 = __builtin_amdgcn_fdot2(hp, w2[1][k], q1, false);
            q2 = __builtin_amdgcn_fdot2(hp, w2[2][k], q2, false);
        }
    };

    // ---- pipelined main loop (8 iterations, fully unrolled) ----
    int    rbC[4]; half2v pwC[4]; int pC;
    int    rbN[4]; half2v pwN[4]; int pN = 0;
    half8  A0[4], A1[4], B0[4], B1[4];

    calc(wave, rbC, pwC, pC);
    loadA(rbC, A0, A1);
    loadB(rbC, B0, B1);

    #pragma unroll
    for (int k = 0; k < 8; ++k) {
        if (k < 7) calc(wave + (k + 1) * stride, rbN, pwN, pN);

        half8 accA = biasA;
        #pragma unroll
        for (int a = 0; a < 4; ++a) {
            accA = A0[a] * pwC[a][0] + accA;
            accA = A1[a] * pwC[a][1] + accA;
        }
        if (k < 7) loadA(rbN, A0, A1);       // prefetch next A-half

        float q0 = 0.f, q1 = 0.f, q2 = 0.f;
        dots(accA, w2A, q0, q1, q2);

        half8 accB = biasB;
        #pragma unroll
        for (int a = 0; a < 4; ++a) {
            accB = B0[a] * pwC[a][0] + accB;
            accB = B1[a] * pwC[a][1] + accB;
        }
        if (k < 7) loadB(rbN, B0, B1);       // prefetch next B-half

        dots(accB, w2B, q0, q1, q2);

        q0 = reduce16(q0);
        q1 = reduce16(q1);
        q2 = reduce16(q2);

        if (l16 == 0) {
            *reinterpret_cast<float3*>(out + 3 * pC) =
                make_float3(q0 + ob0, q1 + ob1, q2 + ob2);
        }

        #pragma unroll
        for (int a = 0; a < 4; ++a) { rbC[a] = rbN[a]; pwC[a] = pwN[a]; }
        pC = pN;
    }
}

extern "C" void kernel_launch(void* const* d_in, const int* in_sizes, int n_in,
                              void* d_out, int out_size, void* d_ws, size_t ws_size,
                              hipStream_t stream) {
    const float* coords = (const float*)d_in[0];
    const float* tables = (const float*)d_in[1];
    const float* W1     = (const float*)d_in[2];
    const float* b1     = (const float*)d_in[3];
    const float* W2     = (const float*)d_in[4];
    const float* b2     = (const float*)d_in[5];
    float* out = (float*)d_out;

    half_t* T2 = (half_t*)d_ws;   // 1 MiB scratch

    hipLaunchKernelGGL(t2_precompute_kernel, dim3(NROWS / 8), dim3(256), 0, stream,
                       tables, W1, T2);
    hipLaunchKernelGGL(eval_kernel, dim3(2048), dim3(256), 0, stream,
                       coords, T2, b1, W2, b2, out);
}